// Round 2
// baseline (353.482 us; speedup 1.0000x reference)
//
#include <hip/hip_runtime.h>

// PDF sampler (NeRF proposal resampling), eval path.
// R=131072 rays, N=256 existing bins, num_samples=96 -> num_bins=97.
// out = [2, R, 97] fp32: [0]=euclidean bins (NEAR + bins*(FAR-NEAR)), [1]=spacing bins.
//
// One wave (64 lanes) per ray:
//   - float4 coalesced load of 256 weights (4/lane)
//   - wave shuffle inclusive scan -> CDF (257 entries) in LDS
//   - spacing row (257 entries) staged to LDS
//   - 97 samples: binary search (searchsorted side='right') + lerp

#define NUM_RAYS 131072
#define NUM_EXISTING 256
#define NUM_BINS 97          // num_samples + 1
#define NEAR_T 2.0f
#define FAR_T 6.0f
#define EPS_W 1e-5f

constexpr int WAVES_PER_BLOCK = 4;
constexpr int BLOCK = 64 * WAVES_PER_BLOCK;
// pad row to 260 floats (1040 B, 16B-aligned) so float4 stores stay aligned
constexpr int ROW = NUM_EXISTING + 4;

__global__ __launch_bounds__(BLOCK) void pdf_sample_kernel(
    const float* __restrict__ weights,
    const float* __restrict__ spacing_starts,
    const float* __restrict__ spacing_ends,
    float* __restrict__ out)
{
    __shared__ float s_cdf[WAVES_PER_BLOCK][ROW]; // [0..256] used
    __shared__ float s_bin[WAVES_PER_BLOCK][ROW]; // [0..256] used

    const int wave = threadIdx.x >> 6;
    const int lane = threadIdx.x & 63;
    const int ray  = blockIdx.x * WAVES_PER_BLOCK + wave;

    const float* wrow = weights        + (size_t)ray * NUM_EXISTING;
    const float* srow = spacing_starts + (size_t)ray * NUM_EXISTING;

    // ---- coalesced loads: 16 B/lane each ----
    float4 w4 = reinterpret_cast<const float4*>(wrow)[lane];
    float4 b4 = reinterpret_cast<const float4*>(srow)[lane];

    float* cdfw = s_cdf[wave];
    float* binw = s_bin[wave];

    reinterpret_cast<float4*>(binw)[lane] = b4;
    if (lane == 0) {
        binw[NUM_EXISTING] = spacing_ends[(size_t)ray * NUM_EXISTING + (NUM_EXISTING - 1)];
        cdfw[0] = 0.0f;
    }

    // ---- wave inclusive scan of per-lane chunk sums ----
    float sl   = (w4.x + w4.y) + (w4.z + w4.w);
    float incl = sl;
    #pragma unroll
    for (int off = 1; off < 64; off <<= 1) {
        float n = __shfl_up(incl, off);
        if (lane >= off) incl += n;
    }
    float total = __shfl(incl, 63);
    float excl  = incl - sl;

    // padding = relu(eps - w_sum); w += padding/N; w_sum += padding
    float padding  = fmaxf(EPS_W - total, 0.0f);
    float pad_each = padding * (1.0f / (float)NUM_EXISTING);
    float inv      = 1.0f / (total + padding);

    float base = (excl + (float)(lane * 4) * pad_each) * inv;
    float p0 = (w4.x + pad_each) * inv;
    float p1 = (w4.y + pad_each) * inv;
    float p2 = (w4.z + pad_each) * inv;
    float p3 = (w4.w + pad_each) * inv;
    float c0 = base + p0;
    float c1 = c0 + p1;
    float c2 = c1 + p2;
    float c3 = c2 + p3;

    int ci = 1 + lane * 4;
    cdfw[ci + 0] = fminf(c0, 1.0f);
    cdfw[ci + 1] = fminf(c1, 1.0f);
    cdfw[ci + 2] = fminf(c2, 1.0f);
    cdfw[ci + 3] = fminf(c3, 1.0f);

    __syncthreads(); // order LDS writes before reads (also covers the lane-0 stores)

    float* out_e = out + (size_t)ray * NUM_BINS;
    float* out_s = out + (size_t)NUM_RAYS * NUM_BINS + (size_t)ray * NUM_BINS;

    constexpr float U_STEP = 1.0f / (float)NUM_BINS;
    constexpr float U_HALF = 0.5f / (float)NUM_BINS;

    #pragma unroll
    for (int it = 0; it < 2; ++it) {
        int j = lane + it * 64;
        if (j < NUM_BINS) {
            // u[j] = j/97 + 1/(2*97)
            float u = fmaf((float)j, U_STEP, U_HALF);

            // searchsorted(cdf, u, side='right'): first idx with cdf[idx] > u
            int lo = 0, hi = NUM_EXISTING + 1; // search over cdf[0..256], insert pos in [0,257]
            while (lo < hi) {
                int mid = (lo + hi) >> 1;
                if (cdfw[mid] <= u) lo = mid + 1; else hi = mid;
            }
            int below = lo - 1; if (below < 0) below = 0; if (below > NUM_EXISTING) below = NUM_EXISTING;
            int above = lo;     if (above > NUM_EXISTING) above = NUM_EXISTING;

            float cg0 = cdfw[below];
            float cg1 = cdfw[above];
            float bg0 = binw[below];
            float bg1 = binw[above];

            float denom = cg1 - cg0;
            denom = (denom < 1e-5f) ? 1.0f : denom;
            float t = (u - cg0) / denom;
            t = fminf(fmaxf(t, 0.0f), 1.0f);

            float bins = fmaf(t, bg1 - bg0, bg0);
            float eucl = fmaf(bins, (FAR_T - NEAR_T), NEAR_T);

            out_e[j] = eucl;
            out_s[j] = bins;
        }
    }
}

extern "C" void kernel_launch(void* const* d_in, const int* in_sizes, int n_in,
                              void* d_out, int out_size, void* d_ws, size_t ws_size,
                              hipStream_t stream) {
    const float* weights        = (const float*)d_in[0];
    const float* spacing_starts = (const float*)d_in[1];
    const float* spacing_ends   = (const float*)d_in[2];
    // d_in[3] = num_samples (int scalar) -- fixed at 96, baked in as NUM_BINS=97
    float* out = (float*)d_out;

    dim3 grid(NUM_RAYS / WAVES_PER_BLOCK);
    dim3 block(BLOCK);
    pdf_sample_kernel<<<grid, block, 0, stream>>>(weights, spacing_starts, spacing_ends, out);
}

// Round 3
// 353.258 us; speedup vs baseline: 1.0006x; 1.0006x over previous
//
#include <hip/hip_runtime.h>

// PDF sampler (NeRF proposal resampling), eval path.
// R=131072 rays, N=256 existing bins, num_samples=96 -> num_bins=97.
// out = [2, R, 97] fp32: [0]=euclidean (NEAR + bins*(FAR-NEAR)), [1]=spacing bins.
//
// One wave per ray. KEY IDEA vs round-2 kernel: u is a uniform grid, so
// searchsorted(cdf, u_j) is inverted analytically: for each cdf entry c,
// m = clamp(ceil(97c - 0.5), 0, 97) is the first sample index with u_j >= c.
// inds[j] = 1 + prefix_sum(histogram(m)) -- no binary search at all.
// All LDS is wave-private: no __syncthreads (DS pipe is in-order per wave).

#define NUM_RAYS 131072
#define NUM_EXISTING 256
#define NUM_BINS 97          // num_samples + 1
#define EPS_W 1e-5f

constexpr int WAVES_PER_BLOCK = 4;
constexpr int BLOCK = 64 * WAVES_PER_BLOCK;
constexpr int ROW  = NUM_EXISTING + 4;  // bins row: [0..256] used, 1040 B (16B mult)
constexpr int CROW = NUM_EXISTING + 4;  // cdfw[k] = cdf[k+1], [0..255] used
constexpr int HROW = 128;               // histogram: [0..97] used, rest zero pad

__global__ __launch_bounds__(BLOCK) void pdf_sample_kernel(
    const float* __restrict__ weights,
    const float* __restrict__ spacing_starts,
    const float* __restrict__ spacing_ends,
    float* __restrict__ out)
{
    __shared__ __align__(16) float s_bin[WAVES_PER_BLOCK][ROW];
    __shared__ __align__(16) float s_cdf[WAVES_PER_BLOCK][CROW];
    __shared__ __align__(16) int   s_h[WAVES_PER_BLOCK][HROW];

    const int wave = threadIdx.x >> 6;
    const int lane = threadIdx.x & 63;
    const int ray  = blockIdx.x * WAVES_PER_BLOCK + wave;

    const float* wrow = weights        + (size_t)ray * NUM_EXISTING;
    const float* srow = spacing_starts + (size_t)ray * NUM_EXISTING;

    // ---- coalesced loads: 16 B/lane each ----
    float4 w4 = reinterpret_cast<const float4*>(wrow)[lane];
    float4 b4 = reinterpret_cast<const float4*>(srow)[lane];

    float* binw = s_bin[wave];
    float* cdfw = s_cdf[wave];
    int*   hw   = s_h[wave];

    reinterpret_cast<float4*>(binw)[lane] = b4;   // bins[4l..4l+3], aligned b128
    if (lane == 0)
        binw[NUM_EXISTING] = spacing_ends[(size_t)ray * NUM_EXISTING + (NUM_EXISTING - 1)];

    // zero histogram (all 128 entries so padded reads below are 0)
    hw[lane]      = 0;
    hw[lane + 64] = 0;

    // ---- wave inclusive scan of per-lane chunk sums ----
    float sl   = (w4.x + w4.y) + (w4.z + w4.w);
    float incl = sl;
    #pragma unroll
    for (int off = 1; off < 64; off <<= 1) {
        float n = __shfl_up(incl, off);
        if (lane >= off) incl += n;
    }
    float total = __shfl(incl, 63);
    float excl  = incl - sl;

    // padding = relu(eps - w_sum); w += padding/N; w_sum += padding
    float padding  = fmaxf(EPS_W - total, 0.0f);
    float pad_each = padding * (1.0f / (float)NUM_EXISTING);
    float inv      = 1.0f / (total + padding);

    float base = (excl + (float)(lane * 4) * pad_each) * inv;
    float cc = base + (w4.x + pad_each) * inv;  float c0 = fminf(cc, 1.0f);
    cc += (w4.y + pad_each) * inv;              float c1 = fminf(cc, 1.0f);
    cc += (w4.z + pad_each) * inv;              float c2 = fminf(cc, 1.0f);
    cc += (w4.w + pad_each) * inv;              float c3 = fminf(cc, 1.0f);

    // cdf[1+4l .. 4+4l] stored at cdfw[4l .. 4l+3] -> aligned ds_write_b128
    float4 cst = make_float4(c0, c1, c2, c3);
    reinterpret_cast<float4*>(cdfw)[lane] = cst;

    // ---- inverse mapping: first sample index m with u_m >= c (O(1) per entry) ----
    // u_j = (j + 0.5)/97  =>  m = clamp(ceil(97c - 0.5), 0, 97)
    #pragma unroll
    for (int k = 0; k < 4; ++k) {
        float c = (k == 0) ? c0 : (k == 1) ? c1 : (k == 2) ? c2 : c3;
        int m = (int)ceilf(fmaf(97.0f, c, -0.5f));
        m = m < 0 ? 0 : (m > 97 ? 97 : m);
        atomicAdd(&hw[m], 1);
    }

    // ---- pair-scan of histogram: inds[j] = 1 + sum_{b<=j} h[b] ----
    int2 hp = *reinterpret_cast<const int2*>(&hw[2 * lane]);  // lanes>48 read zeros
    int v0 = hp.x, v1 = hp.y;
    int ps = v0 + v1;
    int pincl = ps;
    #pragma unroll
    for (int off = 1; off < 64; off <<= 1) {
        int n = __shfl_up(pincl, off);
        if (lane >= off) pincl += n;
    }
    int pexcl = pincl - ps;
    int inds0 = 1 + pexcl + v0;   // inds for j = 2*lane
    int inds1 = inds0 + v1;       // inds for j = 2*lane + 1

    float* out_e = out + (size_t)ray * NUM_BINS;
    float* out_s = out + (size_t)NUM_RAYS * NUM_BINS + (size_t)ray * NUM_BINS;

    constexpr float U_STEP = 1.0f / (float)NUM_BINS;
    constexpr float U_HALF = 0.5f / (float)NUM_BINS;

    #pragma unroll
    for (int k = 0; k < 2; ++k) {
        int j = 2 * lane + k;
        if (j < NUM_BINS) {
            int idx   = (k == 0) ? inds0 : inds1;
            idx       = idx > 256 ? 256 : idx;   // defensive (math gives [1,256])
            int below = idx - 1;                 // [0,255]

            float u = fmaf((float)j, U_STEP, U_HALF);

            // cdf[below], cdf[above]: cdfw[k]=cdf[k+1]; pair read at cb, cb+1
            int cb = below - 1; cb = cb < 0 ? 0 : cb;
            float x = cdfw[cb];
            float y = cdfw[cb + 1];
            float cg0 = (below == 0) ? 0.0f : x;
            float cg1 = (below == 0) ? x    : y;

            float bg0 = binw[below];
            float bg1 = binw[below + 1];

            float denom = cg1 - cg0;
            denom = (denom < 1e-5f) ? 1.0f : denom;
            float t = __fdividef(u - cg0, denom);
            t = fminf(fmaxf(t, 0.0f), 1.0f);

            float bins = fmaf(t, bg1 - bg0, bg0);

            out_e[j] = fmaf(bins, 4.0f, 2.0f);   // NEAR + bins*(FAR-NEAR)
            out_s[j] = bins;
        }
    }
}

extern "C" void kernel_launch(void* const* d_in, const int* in_sizes, int n_in,
                              void* d_out, int out_size, void* d_ws, size_t ws_size,
                              hipStream_t stream) {
    const float* weights        = (const float*)d_in[0];
    const float* spacing_starts = (const float*)d_in[1];
    const float* spacing_ends   = (const float*)d_in[2];
    // d_in[3] = num_samples (int scalar) -- fixed at 96, baked in as NUM_BINS=97
    float* out = (float*)d_out;

    dim3 grid(NUM_RAYS / WAVES_PER_BLOCK);
    dim3 block(BLOCK);
    pdf_sample_kernel<<<grid, block, 0, stream>>>(weights, spacing_starts, spacing_ends, out);
}

// Round 6
// 351.183 us; speedup vs baseline: 1.0065x; 1.0059x over previous
//
#include <hip/hip_runtime.h>

// PDF sampler (NeRF proposal resampling), eval path.
// R=131072 rays, N=256 existing bins, num_samples=96 -> num_bins=97.
// out = [2, R, 97] fp32: [0]=euclidean (NEAR + bins*(FAR-NEAR)), [1]=spacing bins.
//
// One wave per ray. Round-4 structure (DS-pipe minimized):
//  - float4 coalesced loads (weights, spacing_starts)
//  - wave64 inclusive scan via DPP (row_shr 1/2/4/8 + row_bcast 15/31): pure VALU
//  - analytic searchsorted inversion: u is uniform, so entry e covers samples
//    j in [m_e, m_{e+1}) with m = ceil(97c - 0.5). Scatter below=e+1 into a
//    97-int LDS array (init 0). No binary search, no histogram, no atomics.
//  - all LDS wave-private: no __syncthreads (DS is in-order per wave)

#define NUM_RAYS 131072
#define NUM_EXISTING 256
#define NUM_BINS 97
#define EPS_W 1e-5f

constexpr int WAVES_PER_BLOCK = 4;
constexpr int BLOCK = 64 * WAVES_PER_BLOCK;
constexpr int ROW  = NUM_EXISTING + 4;   // bins row: [0..256] used, 16B-mult
constexpr int CROW = NUM_EXISTING;       // cdfw[k] = cdf[k+1], k in [0,255]
constexpr int DROW = 128;                // below_arr: [0..96] used, rest pad

// v += dpp(v) with compile-time dpp_ctrl/row_mask; bound_ctrl=true -> OOB reads 0
template<int CTRL, int RMASK>
__device__ __forceinline__ float scan_add(float v) {
    int t = __builtin_amdgcn_update_dpp(0, __float_as_int(v), CTRL, RMASK, 0xF, true);
    return v + __int_as_float(t);
}

__global__ __launch_bounds__(BLOCK) void pdf_sample_kernel(
    const float* __restrict__ weights,
    const float* __restrict__ spacing_starts,
    const float* __restrict__ spacing_ends,
    float* __restrict__ out)
{
    __shared__ __align__(16) float s_bin[WAVES_PER_BLOCK][ROW];
    __shared__ __align__(16) float s_cdf[WAVES_PER_BLOCK][CROW];
    __shared__ __align__(16) int   s_dn[WAVES_PER_BLOCK][DROW];

    const int wave = threadIdx.x >> 6;
    const int lane = threadIdx.x & 63;
    const int ray  = blockIdx.x * WAVES_PER_BLOCK + wave;

    const float* wrow = weights        + (size_t)ray * NUM_EXISTING;
    const float* srow = spacing_starts + (size_t)ray * NUM_EXISTING;

    float4 w4 = reinterpret_cast<const float4*>(wrow)[lane];
    float4 b4 = reinterpret_cast<const float4*>(srow)[lane];

    float* binw = s_bin[wave];
    float* cdfw = s_cdf[wave];
    int*   dnw  = s_dn[wave];

    reinterpret_cast<float4*>(binw)[lane] = b4;          // aligned ds_write_b128
    if (lane == 0)
        binw[NUM_EXISTING] = spacing_ends[(size_t)ray * NUM_EXISTING + NUM_EXISTING - 1];

    dnw[lane]      = 0;   // init below_arr (writes precede scatter in wave order)
    dnw[lane + 64] = 0;

    // ---- wave64 inclusive scan of per-lane sums, pure-VALU DPP ----
    float sl = (w4.x + w4.y) + (w4.z + w4.w);
    float v = sl;
    v = scan_add<0x111, 0xF>(v);   // row_shr:1
    v = scan_add<0x112, 0xF>(v);   // row_shr:2
    v = scan_add<0x114, 0xF>(v);   // row_shr:4
    v = scan_add<0x118, 0xF>(v);   // row_shr:8
    v = scan_add<0x142, 0xA>(v);   // row_bcast:15 -> rows 1,3
    v = scan_add<0x143, 0xC>(v);   // row_bcast:31 -> rows 2,3
    float incl  = v;
    float total = __int_as_float(__builtin_amdgcn_readlane(__float_as_int(v), 63));
    float excl  = incl - sl;

    // padding = relu(eps - w_sum); w += padding/N; w_sum += padding
    float padding = fmaxf(EPS_W - total, 0.0f);
    float inv     = __builtin_amdgcn_rcpf(total + padding);
    float padinv  = padding * inv * (1.0f / (float)NUM_EXISTING);

    float base = fmaf(excl, inv, (float)(4 * lane) * padinv);
    float cc = base;
    cc = fmaf(w4.x, inv, cc + padinv); float c0 = fminf(cc, 1.0f);
    cc = fmaf(w4.y, inv, cc + padinv); float c1 = fminf(cc, 1.0f);
    cc = fmaf(w4.z, inv, cc + padinv); float c2 = fminf(cc, 1.0f);
    cc = fmaf(w4.w, inv, cc + padinv); float c3 = fminf(cc, 1.0f);

    reinterpret_cast<float4*>(cdfw)[lane] = make_float4(c0, c1, c2, c3);

    // ---- analytic inverse: m = first sample with u >= c ; c in [0,1] -> m in [0,97]
    int m0 = (int)ceilf(fmaf(97.0f, c0, -0.5f));
    int m1 = (int)ceilf(fmaf(97.0f, c1, -0.5f));
    int m2 = (int)ceilf(fmaf(97.0f, c2, -0.5f));
    int m3 = (int)ceilf(fmaf(97.0f, c3, -0.5f));

    int mn = __shfl_down(m0, 1);          // next entry's m (next lane's m0)
    mn = (lane == 63) ? NUM_BINS : mn;    // sentinel past entry 255

    // enforce monotone bounds under fp noise (ranges stay disjoint & gapless)
    int bb3 = min(m3, mn);
    int bb2 = min(m2, bb3);
    int bb1 = min(m1, bb2);
    int bb0 = min(m0, bb1);

    // scatter: entry e = 4*lane+k covers samples [b_k, b_{k+1}) with below = e+1
    int e1 = 4 * lane + 1;
    for (int j = bb0; j < bb1; ++j) dnw[j] = e1;
    for (int j = bb1; j < bb2; ++j) dnw[j] = e1 + 1;
    for (int j = bb2; j < bb3; ++j) dnw[j] = e1 + 2;
    for (int j = bb3; j < mn;  ++j) dnw[j] = e1 + 3;

    // ---- epilogue: 2 samples per lane (j = 2*lane, 2*lane+1) ----
    int2 bl2 = *reinterpret_cast<const int2*>(&dnw[2 * lane]); // 8B-aligned ds_read_b64

    float* out_e = out + (size_t)ray * NUM_BINS;
    float* out_s = out + (size_t)NUM_RAYS * NUM_BINS + (size_t)ray * NUM_BINS;

    constexpr float U_STEP = 1.0f / (float)NUM_BINS;
    constexpr float U_HALF = 0.5f / (float)NUM_BINS;

    #pragma unroll
    for (int k = 0; k < 2; ++k) {
        int j = 2 * lane + k;
        if (j < NUM_BINS) {
            int below = k ? bl2.y : bl2.x;
            below = below > 255 ? 255 : below;        // defensive
            int cb = below - 1; cb = cb < 0 ? 0 : cb;

            float u = fmaf((float)j, U_STEP, U_HALF);

            float x   = cdfw[cb];                     // cdf[below] (when below>0)
            float cg1 = cdfw[below];                  // cdf[below+1]
            float cg0 = (below == 0) ? 0.0f : x;

            float bg0 = binw[below];
            float bg1 = binw[below + 1];

            float denom = cg1 - cg0;
            denom = (denom < 1e-5f) ? 1.0f : denom;
            float t = (u - cg0) * __builtin_amdgcn_rcpf(denom);
            t = fminf(fmaxf(t, 0.0f), 1.0f);

            float bins = fmaf(t, bg1 - bg0, bg0);

            out_e[j] = fmaf(bins, 4.0f, 2.0f);        // NEAR + bins*(FAR-NEAR)
            out_s[j] = bins;
        }
    }
}

extern "C" void kernel_launch(void* const* d_in, const int* in_sizes, int n_in,
                              void* d_out, int out_size, void* d_ws, size_t ws_size,
                              hipStream_t stream) {
    const float* weights        = (const float*)d_in[0];
    const float* spacing_starts = (const float*)d_in[1];
    const float* spacing_ends   = (const float*)d_in[2];
    // d_in[3] = num_samples (int scalar) -- fixed at 96, baked in as NUM_BINS=97
    float* out = (float*)d_out;

    dim3 grid(NUM_RAYS / WAVES_PER_BLOCK);
    dim3 block(BLOCK);
    pdf_sample_kernel<<<grid, block, 0, stream>>>(weights, spacing_starts, spacing_ends, out);
}